// Round 7
// baseline (258.691 us; speedup 1.0000x reference)
//
#include <hip/hip_runtime.h>

// Gridding: B batches of N float3 points -> per-batch 64^3 grid of trilinear
// scatter weights.
//
// R11: R10 post-mortem: the u64 coord-pack traded 45K cyc/CU of DS for
// +46K cyc/SIMD of scan VALU (pack runs on ~every wave-visit) — net loss.
// R9 post-mortem: index-queue's global re-gather stalled the drain. This
// round combines the verified-good parts of each, none of the bad:
//  - 4-parity grids, TH=4/NSLAB=16 (R9's verified heavy/decode): EXACTLY
//    2 u64 atomics per point = 16.8M lane-atomics = 118K cyc/CU — the
//    floor for u16 fields in u64 words (8 corner weights need 128 bits).
//  - Queue payload = RAW float bits, SoA per wave: float2{px,py} (aligned
//    -> one ds_write_b64) + float{pz} (ds_write_b32). ZERO pack/unpack
//    VALU; no VMEM in the drain; output bit-identical to R8 (exact coords,
//    integer atomic adds commute).
//  - Slim scan test: pass <=> px in [lo_k, hi_k) && sum!=0, with scalar
//    bounds lo=(4k-33)/32, hi=(4k-28)/32 (exact fp32; equivalent to the
//    ix-clamp test; k=0 -> lo=-inf, k=15 -> hi=+inf). ~16 cyc/pt, so
//    NSLAB=16 total scan VALU is still ~half of R10's.
//  - Ledger/CU: DS = atomics 118K + qwrite 36K + qread 3K + misc 8K
//    ~ 165K cyc ~ 69 us; VALU ~ 60K cyc ~ 25 us (hidden under DS).
//  - Grid (B, NSLAB): 512 wgs, 2 rounds; 8 same-batch blocks resident in
//    lockstep per round -> R9-measured FETCH ~99 MB (hidden).
//  - LDS: 128K grids + 16K qxy + 8K qz = 155648 B (R8-proven size).

#define GS    64
#define G2    (GS * GS)          // 4096
#define G3    (GS * GS * GS)     // 262144
#define SHALF 32                 // scale (half-extent)
#define TH    4                  // planes per slab
#define NSLAB (GS / TH)          // 16
#define TPB   1024
#define NWAVE (TPB / 64)         // 16
#define QCAP  128                // per-wave queue capacity (qn<64 + push<=64)
#define NGW   (4 * TH * 1024)    // u64 words: 4 parity grids x TH x 1024 tiles

#define QSF   1024.0f            // weight quantization scale (2^10)
#define QDEC  (1.0f / 1024.0f)

typedef unsigned long long ull;

__device__ __forceinline__ ull pack4(unsigned q00, unsigned q01,
                                     unsigned q10, unsigned q11) {
    // field f = dy*2+dz at bits [16f, 16f+16)
    return (ull)q00 | ((ull)q01 << 16) | ((ull)q10 << 32) | ((ull)q11 << 48);
}

// Heavy body: weights, quantize, 2 packed LDS atomics into parity grids.
// Precondition: point passed the slab-membership and zero-mask tests.
__device__ __forceinline__ void heavy(float px, float py, float pz, int k,
                                      ull* __restrict__ g64) {
    float x = px * (float)SHALF;
    float y = py * (float)SHALF;
    float z = pz * (float)SHALF;

    float lx = floorf(x), ly = floorf(y), lz = floorf(z);
    int ix = min(max((int)lx + SHALF, 0), GS - 2);
    int iy = min(max((int)ly + SHALF, 0), GS - 2);
    int iz = min(max((int)lz + SHALF, 0), GS - 2);
    int rel = ix - TH * k;
    if ((unsigned)(rel + 1) > TH) return;    // insurance; never true (exact)

    float fx = x - lx, fy = y - ly, fz = z - lz;
    float wx0 = (1.0f - fx) * ((rel >= 0)      ? 1.0f : 0.0f);
    float wx1 = fx          * ((rel <= TH - 2) ? 1.0f : 0.0f);
    int plo = max(rel, 0);
    int phi = min(rel + 1, TH - 1);

    float wy0 = 1.0f - fy, wy1 = fy;
    float wz0 = 1.0f - fz, wz1 = fz;
    float a00 = wx0 * wy0, a01 = wx0 * wy1;
    float b00 = wx1 * wy0, b01 = wx1 * wy1;

    // quantize (round-half-up; all weights >= 0). q[plane][dy][dz]
    unsigned qa00z0 = (unsigned)(a00 * wz0 * QSF + 0.5f);
    unsigned qa00z1 = (unsigned)(a00 * wz1 * QSF + 0.5f);
    unsigned qa01z0 = (unsigned)(a01 * wz0 * QSF + 0.5f);
    unsigned qa01z1 = (unsigned)(a01 * wz1 * QSF + 0.5f);
    unsigned qb00z0 = (unsigned)(b00 * wz0 * QSF + 0.5f);
    unsigned qb00z1 = (unsigned)(b00 * wz1 * QSF + 0.5f);
    unsigned qb01z0 = (unsigned)(b01 * wz0 * QSF + 0.5f);
    unsigned qb01z1 = (unsigned)(b01 * wz1 * QSF + 0.5f);

    // parity grid: quad (iy..iy+1, iz..iz+1) is tile-aligned in grid g
    const int g = ((iy & 1) << 1) | (iz & 1);
    const int t = ((iy >> 1) << 5) + (iz >> 1);        // tile within plane

    ull va = pack4(qa00z0, qa00z1, qa01z0, qa01z1);
    ull vb = pack4(qb00z0, qb00z1, qb01z0, qb01z1);
    if (va) atomicAdd(&g64[((g * TH + plo) << 10) + t], va);
    if (vb) atomicAdd(&g64[((g * TH + phi) << 10) + t], vb);
}

// slim test + ballot-compacted raw-payload push; drains 64 at full occupancy
__device__ __forceinline__ void push_pt(float px, float py, float pz,
                                        float lo, float hi, int k, int lane,
                                        float2* __restrict__ qxy,
                                        float* __restrict__ qz, int& qn,
                                        ull* __restrict__ g64) {
    // membership: px in [lo, hi)  <=>  ix(clamped) in [4k-1, 4k+3]
    // (bounds are integer/32, exact in fp32; sentinels handle k=0/15 clamps)
    bool pass = (px >= lo) & (px < hi) & ((px + py + pz) != 0.0f);
    ull m = __ballot(pass);
    if (pass) {
        int idx = qn + (int)__popcll(m & ((1ull << lane) - 1));
        qxy[idx] = make_float2(px, py);   // aligned -> ds_write_b64
        qz[idx]  = pz;                    // ds_write_b32
    }
    qn += (int)__popcll(m);          // wave-uniform
    if (qn >= 64) {                  // wave-uniform branch (SGPR compare)
        qn -= 64;
        float2 xy = qxy[qn + lane];
        float  z  = qz[qn + lane];
        heavy(xy.x, xy.y, z, k, g64);
    }
}

__global__ __launch_bounds__(TPB, 1) void gridding_u16_kernel(
    const float* __restrict__ pt, float* __restrict__ out, int N) {
    __shared__ ull    g64[NGW];             // 128 KB: 4 parity grids
    __shared__ float2 qxy[NWAVE * QCAP];    // 16 KB: per-wave (x,y) queues
    __shared__ float  qz [NWAVE * QCAP];    //  8 KB: per-wave z queues

    const int b    = blockIdx.x;   // batch (8 same-batch blocks/round)
    const int k    = blockIdx.y;   // slab (4 planes)
    const int tid  = threadIdx.x;
    const int wid  = tid >> 6;
    const int lane = tid & 63;

    for (int t = tid; t < NGW; t += TPB) g64[t] = 0ull;
    __syncthreads();

    // slab bounds in raw-point units (exact: integer/32)
    const float lo = (k == 0)         ? -1e30f
                                      : (float)(TH * k - 33) * (1.0f / 32.0f);
    const float hi = (k == NSLAB - 1) ? 1e30f
                                      : (float)(TH * k - 28) * (1.0f / 32.0f);

    const float4* p4 = (const float4*)(pt + (size_t)b * N * 3);
    float2* qxyw = qxy + wid * QCAP;
    float*  qzw  = qz  + wid * QCAP;
    int     qn   = 0;

    const int nq    = N >> 2;          // 4-point quads
    const int niter = nq / TPB;        // exact (launcher guards N%(4*TPB)==0)

    for (int it = 0; it < niter; ++it) {
        int qd = it * TPB + tid;
        float4 A = p4[3 * qd + 0], Bv = p4[3 * qd + 1], C = p4[3 * qd + 2];
        push_pt(A.x,  A.y,  A.z,  lo, hi, k, lane, qxyw, qzw, qn, g64);
        push_pt(A.w,  Bv.x, Bv.y, lo, hi, k, lane, qxyw, qzw, qn, g64);
        push_pt(Bv.z, Bv.w, C.x,  lo, hi, k, lane, qxyw, qzw, qn, g64);
        push_pt(C.y,  C.z,  C.w,  lo, hi, k, lane, qxyw, qzw, qn, g64);
    }
    // tail drain (qn in [0,63], wave-uniform)
    if (lane < qn) {
        float2 xy = qxyw[lane];
        float  z  = qzw[lane];
        heavy(xy.x, xy.y, z, k, g64);
    }
    __syncthreads();

    // decode: cell (pl,y,z) = sum over parity grids g=(gy,gz) of the u16 at
    // tile ((y-gy)>>1,(z-gz)>>1), field ((y-gy)&1)*2+((z-gz)&1)
    const unsigned short* g16 = (const unsigned short*)g64;
    float* ob = out + (size_t)b * G3 + (size_t)(TH * k) * G2;
    for (int t = tid; t < TH * G2; t += TPB) {
        int pl = t >> 12;
        int cell = t & 4095;
        int y = cell >> 6, z = cell & 63;
        unsigned v = 0;
#pragma unroll
        for (int gy = 0; gy < 2; ++gy) {
#pragma unroll
            for (int gz = 0; gz < 2; ++gz) {
                if (y >= gy && z >= gz) {
                    int my = (y - gy) >> 1, mz = (z - gz) >> 1;
                    int f  = (((y - gy) & 1) << 1) | ((z - gz) & 1);
                    int g  = (gy << 1) | gz;
                    v += g16[((((g * TH + pl) << 10) + (my << 5) + mz) << 2) + f];
                }
            }
        }
        ob[t] = (float)v * QDEC;
    }
}

// ---- fallback (general shapes): R1 atomic kernel ----
__global__ void gridding_atomic_kernel(const float* __restrict__ pt,
                                       float* __restrict__ out, int P, int N) {
    int i = blockIdx.x * blockDim.x + threadIdx.x;
    if (i >= P) return;
    int b = i / N;
    float x = pt[3 * i + 0] * (float)SHALF;
    float y = pt[3 * i + 1] * (float)SHALF;
    float z = pt[3 * i + 2] * (float)SHALF;
    const float m = ((x + y + z) != 0.0f) ? 1.0f : 0.0f;
    float lx = floorf(x), ly = floorf(y), lz = floorf(z);
    float fx = x - lx, fy = y - ly, fz = z - lz;
    int ix = min(max((int)lx + SHALF, 0), GS - 2);
    int iy = min(max((int)ly + SHALF, 0), GS - 2);
    int iz = min(max((int)lz + SHALF, 0), GS - 2);
    float* base = out + (size_t)b * G3 + ((ix * GS + iy) * GS + iz);
    float wx0 = (1.0f - fx) * m, wx1 = fx * m;
    float w00 = wx0 * (1.0f - fy), w01 = wx0 * fy;
    float w10 = wx1 * (1.0f - fy), w11 = wx1 * fy;
    atomicAdd(base,               w00 * (1.0f - fz));
    atomicAdd(base + 1,           w00 * fz);
    atomicAdd(base + GS,          w01 * (1.0f - fz));
    atomicAdd(base + GS + 1,      w01 * fz);
    atomicAdd(base + G2,          w10 * (1.0f - fz));
    atomicAdd(base + G2 + 1,      w10 * fz);
    atomicAdd(base + G2 + GS,     w11 * (1.0f - fz));
    atomicAdd(base + G2 + GS + 1, w11 * fz);
}

extern "C" void kernel_launch(void* const* d_in, const int* in_sizes, int n_in,
                              void* d_out, int out_size, void* d_ws, size_t ws_size,
                              hipStream_t stream) {
    const float* pt  = (const float*)d_in[0];
    float*       out = (float*)d_out;

    const int P = in_sizes[0] / 3;       // total points (B*N)
    const int B = out_size / G3;         // 32
    const int N = (B > 0) ? P / B : 0;   // 262144

    const bool fast = (B > 0) && (out_size == B * G3) && (P == B * N) &&
                      (N % (4 * TPB) == 0);

    if (fast) {
        dim3 g(B, NSLAB);                // 512 wgs (2 rounds over 256 CUs)
        gridding_u16_kernel<<<g, TPB, 0, stream>>>(pt, out, N);
    } else {
        hipMemsetAsync(d_out, 0, (size_t)out_size * sizeof(float), stream);
        gridding_atomic_kernel<<<(P + 255) / 256, 256, 0, stream>>>(pt, out, P, N);
    }
}

// Round 8
// 212.110 us; speedup vs baseline: 1.2196x; 1.2196x over previous
//
#include <hip/hip_runtime.h>

// Gridding: B batches of N float3 points -> per-batch 64^3 grid of trilinear
// scatter weights.
//
// R12: R11 post-mortem: TH=4's 2 rounds doubled the ~150cyc/visit scan and
// thrashed the LLC (FETCH 49->98MB) — the 4-parity atomic win (118K vs 177K
// cyc/CU) can't pay for it. Structural law: chip LDS = 40MB; 2-grid scheme
// = 32MB/full-grid -> ONE round (R8's shape is the capacity optimum);
// 4-parity = 64MB -> 2 rounds. So: keep R8's verified one-round TH=8 2-grid
// structure and graft in ONLY the two R11-verified micro-wins:
//  - slim scan test: pass <=> px in [lo_k,hi_k) && sum!=0, lo=(8k-33)/32,
//    hi=(8k-24)/32 (exact fp32; proven == ix-clamp test incl. clamp edges;
//    k=0 -> lo=-inf, k=7 -> hi=+inf). ~Halves per-visit scan VALU.
//  - queue payload = raw floats, SoA: float2{px,py} (1 ds_write_b64) +
//    float{pz} (1 ds_write_b32) — 2 DS ops/push (was 3), zero pack VALU,
//    no VMEM in drain. Queue DS 74K -> ~41K cyc/CU.
// Heavy scatter / decode / init byte-identical to R8 -> output bit-identical
// (absmax exactly 0.03125).
// Ledger/CU: DS = atomics 177K + queue 41K + drainrd 6K + misc 15K ~ 239K
// cyc ~ 100 us; VALU ~ 115K (hidden). Predicted 100-106 us.
// LDS: 2x64K grids + 16K qxy + 8K qz = 155648 B, 1 blk/CU, 256 wgs.

#define GS    64
#define G2    (GS * GS)          // 4096
#define G3    (GS * GS * GS)     // 262144
#define SHALF 32                 // scale (half-extent)
#define TH    8                  // planes per slab
#define NSLAB (GS / TH)          // 8
#define TPB   1024
#define NWG   (TH * 1024)        // u64 words per grid (8 planes x 1024 tiles)
#define NWAVE (TPB / 64)         // 16
#define QCAP  128                // per-wave queue capacity (qn<64 + push<=64)

#define QSF   1024.0f            // weight quantization scale (2^10)
#define QDEC  (1.0f / 1024.0f)

typedef unsigned long long ull;

__device__ __forceinline__ ull pack4(unsigned q00, unsigned q01,
                                     unsigned q10, unsigned q11) {
    // field f = dy*2+dz at bits [16f, 16f+16)
    return (ull)q00 | ((ull)q01 << 16) | ((ull)q10 << 32) | ((ull)q11 << 48);
}

// R8 heavy body (verbatim scatter): weights, quantize, dual-grid packed LDS
// atomics. Takes RAW point coords; precondition: passed slim test.
__device__ __forceinline__ void heavy(float px, float py, float pz, int k,
                                      ull* __restrict__ A64,
                                      ull* __restrict__ B64) {
    float x = px * (float)SHALF;
    float y = py * (float)SHALF;
    float z = pz * (float)SHALF;

    float lx = floorf(x), ly = floorf(y), lz = floorf(z);
    int ix = min(max((int)lx + SHALF, 0), GS - 2);
    int iy = min(max((int)ly + SHALF, 0), GS - 2);
    int iz = min(max((int)lz + SHALF, 0), GS - 2);
    int rel = ix - TH * k;
    if ((unsigned)(rel + 1) > TH) return;    // insurance; proven never true

    float fx = x - lx, fy = y - ly, fz = z - lz;
    float wx0 = (1.0f - fx) * ((rel >= 0)      ? 1.0f : 0.0f);
    float wx1 = fx          * ((rel <= TH - 2) ? 1.0f : 0.0f);
    int plo = max(rel, 0);
    int phi = min(rel + 1, TH - 1);

    float wy0 = 1.0f - fy, wy1 = fy;
    float wz0 = 1.0f - fz, wz1 = fz;
    float a00 = wx0 * wy0, a01 = wx0 * wy1;
    float b00 = wx1 * wy0, b01 = wx1 * wy1;

    // quantize (round-half-up; all weights >= 0). q[plane][dy][dz]
    unsigned qa00z0 = (unsigned)(a00 * wz0 * QSF + 0.5f);
    unsigned qa00z1 = (unsigned)(a00 * wz1 * QSF + 0.5f);
    unsigned qa01z0 = (unsigned)(a01 * wz0 * QSF + 0.5f);
    unsigned qa01z1 = (unsigned)(a01 * wz1 * QSF + 0.5f);
    unsigned qb00z0 = (unsigned)(b00 * wz0 * QSF + 0.5f);
    unsigned qb00z1 = (unsigned)(b00 * wz1 * QSF + 0.5f);
    unsigned qb01z0 = (unsigned)(b01 * wz0 * QSF + 0.5f);
    unsigned qb01z1 = (unsigned)(b01 * wz1 * QSF + 0.5f);

    const int t0  = (iy >> 1) * 32 + (iz >> 1);  // tile word within plane
    const int wlo = plo * 1024 + t0;
    const int whi = phi * 1024 + t0;
    const int dy = iy & 1, dz = iz & 1;

    if (dy == dz) {
        // whole 2x2 quad lives in one tile of A (even,even) or B (odd,odd)
        ull* g = dy ? B64 : A64;
        ull va = pack4(qa00z0, qa00z1, qa01z0, qa01z1);
        ull vb = pack4(qb00z0, qb00z1, qb01z0, qb01z1);
        if (va) atomicAdd(&g[wlo], va);
        if (vb) atomicAdd(&g[whi], vb);
    } else if (dz) {
        // iy even, iz odd: z-straddle in A -> tiles t0 (fields 1,3), t0+1 (0,2)
        ull va1 = ((ull)qa00z0 << 16) | ((ull)qa01z0 << 48);
        ull va2 = ((ull)qa00z1)       | ((ull)qa01z1 << 32);
        ull vb1 = ((ull)qb00z0 << 16) | ((ull)qb01z0 << 48);
        ull vb2 = ((ull)qb00z1)       | ((ull)qb01z1 << 32);
        if (va1) atomicAdd(&A64[wlo],     va1);
        if (va2) atomicAdd(&A64[wlo + 1], va2);
        if (vb1) atomicAdd(&A64[whi],     vb1);
        if (vb2) atomicAdd(&A64[whi + 1], vb2);
    } else {
        // iy odd, iz even: y-straddle in A -> tiles t0 (fields 2,3), t0+32 (0,1)
        ull va1 = ((ull)qa00z0 << 32) | ((ull)qa00z1 << 48);
        ull va2 = ((ull)qa01z0)       | ((ull)qa01z1 << 16);
        ull vb1 = ((ull)qb00z0 << 32) | ((ull)qb00z1 << 48);
        ull vb2 = ((ull)qb01z0)       | ((ull)qb01z1 << 16);
        if (va1) atomicAdd(&A64[wlo],      va1);
        if (va2) atomicAdd(&A64[wlo + 32], va2);
        if (vb1) atomicAdd(&A64[whi],      vb1);
        if (vb2) atomicAdd(&A64[whi + 32], vb2);
    }
}

// slim test + ballot-compacted raw-payload push; drains 64 at full occupancy
__device__ __forceinline__ void push_pt(float px, float py, float pz,
                                        float lo, float hi, int k, int lane,
                                        float2* __restrict__ qxy,
                                        float* __restrict__ qz, int& qn,
                                        ull* __restrict__ A64,
                                        ull* __restrict__ B64) {
    // membership: px in [lo, hi)  <=>  ix(clamped) in [8k-1, 8k+7]
    bool pass = (px >= lo) & (px < hi) & ((px + py + pz) != 0.0f);
    ull m = __ballot(pass);
    if (pass) {
        int idx = qn + (int)__popcll(m & ((1ull << lane) - 1));
        qxy[idx] = make_float2(px, py);   // aligned -> ds_write_b64
        qz[idx]  = pz;                    // ds_write_b32
    }
    qn += (int)__popcll(m);          // wave-uniform
    if (qn >= 64) {                  // wave-uniform branch (SGPR compare)
        qn -= 64;
        float2 xy = qxy[qn + lane];
        float  z  = qz[qn + lane];
        heavy(xy.x, xy.y, z, k, A64, B64);
    }
}

__global__ __launch_bounds__(TPB, 1) void gridding_u16_kernel(
    const float* __restrict__ pt, float* __restrict__ out, int N) {
    __shared__ ull    A64[NWG];             // 64 KB: even-aligned 2x2 tiles
    __shared__ ull    B64[NWG];             // 64 KB: (1,1)-offset tiles
    __shared__ float2 qxy[NWAVE * QCAP];    // 16 KB: per-wave (x,y) queues
    __shared__ float  qz [NWAVE * QCAP];    //  8 KB: per-wave z queues

    const int b    = blockIdx.x;   // batch (b%8 XCD affinity)
    const int k    = blockIdx.y;   // slab (8 planes)
    const int tid  = threadIdx.x;
    const int wid  = tid >> 6;
    const int lane = tid & 63;

    for (int t = tid; t < NWG; t += TPB) { A64[t] = 0ull; B64[t] = 0ull; }
    __syncthreads();

    // slab bounds in raw-point units (integer/32, exact in fp32)
    const float lo = (k == 0)         ? -1e30f
                                      : (float)(TH * k - 33) * (1.0f / 32.0f);
    const float hi = (k == NSLAB - 1) ? 1e30f
                                      : (float)(TH * k - 24) * (1.0f / 32.0f);

    const float4* p4 = (const float4*)(pt + (size_t)b * N * 3);
    float2* qxyw = qxy + wid * QCAP;
    float*  qzw  = qz  + wid * QCAP;
    int     qn   = 0;

    const int nq    = N >> 2;          // 4-point quads
    const int niter = nq / TPB;        // exact (launcher guards N%(4*TPB)==0)

    for (int it = 0; it < niter; ++it) {
        int qd = it * TPB + tid;
        float4 A = p4[3 * qd + 0], Bv = p4[3 * qd + 1], C = p4[3 * qd + 2];
        push_pt(A.x,  A.y,  A.z,  lo, hi, k, lane, qxyw, qzw, qn, A64, B64);
        push_pt(A.w,  Bv.x, Bv.y, lo, hi, k, lane, qxyw, qzw, qn, A64, B64);
        push_pt(Bv.z, Bv.w, C.x,  lo, hi, k, lane, qxyw, qzw, qn, A64, B64);
        push_pt(C.y,  C.z,  C.w,  lo, hi, k, lane, qxyw, qzw, qn, A64, B64);
    }
    // tail drain (qn in [0,63], wave-uniform)
    if (lane < qn) {
        float2 xy = qxyw[lane];
        float  z  = qzw[lane];
        heavy(xy.x, xy.y, z, k, A64, B64);
    }
    __syncthreads();

    // decode: cell (pl, iy, iz) = A[tile(iy,iz)] + B[tile(iy-1,iz-1)]
    const unsigned short* a16 = (const unsigned short*)A64;
    const unsigned short* b16 = (const unsigned short*)B64;
    float* ob = out + (size_t)b * G3 + (size_t)(TH * k) * G2;
    for (int t = tid; t < TH * G2; t += TPB) {
        int pl = t >> 12;
        int cell = t & 4095;
        int iy = cell >> 6, iz = cell & 63;
        unsigned v = a16[(pl << 12) +
                         (((iy >> 1) * 32 + (iz >> 1)) << 2) +
                         ((iy & 1) << 1) + (iz & 1)];
        if (iy > 0 && iz > 0) {
            v += b16[(pl << 12) +
                     ((((iy - 1) >> 1) * 32 + ((iz - 1) >> 1)) << 2) +
                     (((iy - 1) & 1) << 1) + ((iz - 1) & 1)];
        }
        ob[t] = (float)v * QDEC;
    }
}

// ---- fallback (general shapes): R1 atomic kernel ----
__global__ void gridding_atomic_kernel(const float* __restrict__ pt,
                                       float* __restrict__ out, int P, int N) {
    int i = blockIdx.x * blockDim.x + threadIdx.x;
    if (i >= P) return;
    int b = i / N;
    float x = pt[3 * i + 0] * (float)SHALF;
    float y = pt[3 * i + 1] * (float)SHALF;
    float z = pt[3 * i + 2] * (float)SHALF;
    const float m = ((x + y + z) != 0.0f) ? 1.0f : 0.0f;
    float lx = floorf(x), ly = floorf(y), lz = floorf(z);
    float fx = x - lx, fy = y - ly, fz = z - lz;
    int ix = min(max((int)lx + SHALF, 0), GS - 2);
    int iy = min(max((int)ly + SHALF, 0), GS - 2);
    int iz = min(max((int)lz + SHALF, 0), GS - 2);
    float* base = out + (size_t)b * G3 + ((ix * GS + iy) * GS + iz);
    float wx0 = (1.0f - fx) * m, wx1 = fx * m;
    float w00 = wx0 * (1.0f - fy), w01 = wx0 * fy;
    float w10 = wx1 * (1.0f - fy), w11 = wx1 * fy;
    atomicAdd(base,               w00 * (1.0f - fz));
    atomicAdd(base + 1,           w00 * fz);
    atomicAdd(base + GS,          w01 * (1.0f - fz));
    atomicAdd(base + GS + 1,      w01 * fz);
    atomicAdd(base + G2,          w10 * (1.0f - fz));
    atomicAdd(base + G2 + 1,      w10 * fz);
    atomicAdd(base + G2 + GS,     w11 * (1.0f - fz));
    atomicAdd(base + G2 + GS + 1, w11 * fz);
}

extern "C" void kernel_launch(void* const* d_in, const int* in_sizes, int n_in,
                              void* d_out, int out_size, void* d_ws, size_t ws_size,
                              hipStream_t stream) {
    const float* pt  = (const float*)d_in[0];
    float*       out = (float*)d_out;

    const int P = in_sizes[0] / 3;       // total points (B*N)
    const int B = out_size / G3;         // 32
    const int N = (B > 0) ? P / B : 0;   // 262144

    const bool fast = (B > 0) && (out_size == B * G3) && (P == B * N) &&
                      (N % (4 * TPB) == 0);

    if (fast) {
        dim3 g(B, NSLAB);                // 256 wgs = 1/CU, one round
        gridding_u16_kernel<<<g, TPB, 0, stream>>>(pt, out, N);
    } else {
        hipMemsetAsync(d_out, 0, (size_t)out_size * sizeof(float), stream);
        gridding_atomic_kernel<<<(P + 255) / 256, 256, 0, stream>>>(pt, out, P, N);
    }
}